// Round 1
// baseline (269.803 us; speedup 1.0000x reference)
//
#include <hip/hip_runtime.h>
#include <hip/hip_bf16.h>

#define D 128
#define SCAN_BLK 256
#define SCAN_VPT 4
#define SCAN_TILE (SCAN_BLK * SCAN_VPT)   // 1024 elements per scan block

#define KC 112        // edges per LDS chunk in sage_out
#define HROW 272      // bytes per staged h row (256 data + 16 pad -> spreads bank groups)

typedef __attribute__((ext_vector_type(8))) short short8;   // 8 bf16 = 4 VGPR
typedef __attribute__((ext_vector_type(4))) float f32x4;    // MFMA C/D frag

// ---------------------------------------------------------------------------
// prep_w: WTl/WTr = bf16 transpose of Wl/Wr ([n][k] layout, 16B B-fragments);
// bsum = bl + br.
// ---------------------------------------------------------------------------
__global__ __launch_bounds__(256) void prep_w(
    const float* __restrict__ Wl, const float* __restrict__ Wr,
    const float* __restrict__ bl, const float* __restrict__ br,
    __hip_bfloat16* __restrict__ WTl, __hip_bfloat16* __restrict__ WTr,
    float* __restrict__ bsum) {
  const int tid = blockIdx.x * 256 + threadIdx.x;  // grid 128 -> 0..32767
  const int n = (tid >> 7) & 127;
  const int k = tid & 127;
  if (tid < 16384) {
    WTl[n * D + k] = __float2bfloat16(Wl[k * D + n]);
  } else {
    WTr[n * D + k] = __float2bfloat16(Wr[k * D + n]);
  }
  if (tid < 128) bsum[tid] = bl[tid] + br[tid];
}

// ---------------------------------------------------------------------------
// gemm_h: h = bf16(x @ Wl). Also absorbs the degree histogram as a
// grid-stride prologue (atomics overlap with other waves' MFMA).
// Per 16-row tile: 4 waves x 2 col-tiles of 16. B-frags preloaded once.
// ---------------------------------------------------------------------------
__global__ __launch_bounds__(256) void gemm_h(
    const float* __restrict__ x, const __hip_bfloat16* __restrict__ WTl,
    __hip_bfloat16* __restrict__ h,
    const int* __restrict__ edst, int* __restrict__ deg, int n_edges,
    int n_rowtiles) {
  // histogram prologue
  const int gsz = gridDim.x * 256;
  for (int e = blockIdx.x * 256 + threadIdx.x; e < n_edges; e += gsz)
    atomicAdd(&deg[edst[e]], 1);

  __shared__ __hip_bfloat16 xs[16][136];   // +8 pad
  const int t = threadIdx.x;
  const int wave = t >> 6;
  const int lane = t & 63;
  const int m = lane & 15;
  const int q = lane >> 4;

  short8 bfrag[2][4];
#pragma unroll
  for (int c = 0; c < 2; ++c) {
    const int n0 = wave * 32 + c * 16;
#pragma unroll
    for (int ks = 0; ks < 4; ++ks)
      bfrag[c][ks] = *(const short8*)&WTl[(n0 + m) * D + ks * 32 + q * 8];
  }

  const int srow = t >> 4;
  const int scol = (t & 15) * 8;

  for (int rt = blockIdx.x; rt < n_rowtiles; rt += gridDim.x) {
    const int rowbase = rt * 16;
    {
      const float4* src = (const float4*)&x[(size_t)(rowbase + srow) * D + scol];
      const float4 v0 = src[0], v1 = src[1];
      __hip_bfloat16* dst = &xs[srow][scol];
      dst[0] = __float2bfloat16(v0.x); dst[1] = __float2bfloat16(v0.y);
      dst[2] = __float2bfloat16(v0.z); dst[3] = __float2bfloat16(v0.w);
      dst[4] = __float2bfloat16(v1.x); dst[5] = __float2bfloat16(v1.y);
      dst[6] = __float2bfloat16(v1.z); dst[7] = __float2bfloat16(v1.w);
    }
    __syncthreads();

    f32x4 acc[2];
#pragma unroll
    for (int c = 0; c < 2; ++c)
#pragma unroll
      for (int r = 0; r < 4; ++r) acc[c][r] = 0.f;

#pragma unroll
    for (int ks = 0; ks < 4; ++ks) {
      const short8 afrag = *(const short8*)&xs[m][ks * 32 + q * 8];
#pragma unroll
      for (int c = 0; c < 2; ++c)
        acc[c] = __builtin_amdgcn_mfma_f32_16x16x32_bf16(afrag, bfrag[c][ks], acc[c], 0, 0, 0);
    }

#pragma unroll
    for (int c = 0; c < 2; ++c) {
      const int n = wave * 32 + c * 16 + m;
#pragma unroll
      for (int r = 0; r < 4; ++r)
        h[(size_t)(rowbase + q * 4 + r) * D + n] = __float2bfloat16(acc[c][r]);
    }
    __syncthreads();
  }
}

// ---------------------------------------------------------------------------
// scan1: block-level exclusive scan of deg -> offsets + per-block totals.
// ---------------------------------------------------------------------------
__global__ __launch_bounds__(SCAN_BLK) void scan1_kernel(
    const int* __restrict__ deg, int* __restrict__ offsets,
    int* __restrict__ partials, int n) {
  __shared__ int sdata[SCAN_BLK];
  const int t = threadIdx.x;
  const int base = blockIdx.x * SCAN_TILE + t * SCAN_VPT;

  int v[SCAN_VPT];
  int s = 0;
#pragma unroll
  for (int j = 0; j < SCAN_VPT; ++j) {
    v[j] = (base + j < n) ? deg[base + j] : 0;
    s += v[j];
  }
  sdata[t] = s;
  __syncthreads();
  for (int off = 1; off < SCAN_BLK; off <<= 1) {
    int xv = (t >= off) ? sdata[t - off] : 0;
    __syncthreads();
    sdata[t] += xv;
    __syncthreads();
  }
  int excl = sdata[t] - s;
  if (t == SCAN_BLK - 1) partials[blockIdx.x] = sdata[t];
  int run = excl;
#pragma unroll
  for (int j = 0; j < SCAN_VPT; ++j) {
    if (base + j < n) offsets[base + j] = run;
    run += v[j];
  }
}

// ---------------------------------------------------------------------------
// scan3: adds block-prefix (computed inline by wave 0 — scan2 folded in),
// materializes pos[] cursors and offsets[n] = E.
// ---------------------------------------------------------------------------
__global__ __launch_bounds__(SCAN_BLK) void scan3_kernel(
    int* __restrict__ offsets, int* __restrict__ pos,
    const int* __restrict__ partials, int n, int n_edges) {
  __shared__ int s_add;
  const int t = threadIdx.x;
  if (t < 64) {
    int v = 0;
    for (int j = t; j < blockIdx.x; j += 64) v += partials[j];
#pragma unroll
    for (int off = 32; off > 0; off >>= 1) v += __shfl_down(v, off);
    if (t == 0) s_add = v;
  }
  __syncthreads();
  const int add = s_add;
  const int base = blockIdx.x * SCAN_TILE + t * SCAN_VPT;
#pragma unroll
  for (int j = 0; j < SCAN_VPT; ++j) {
    const int i = base + j;
    if (i < n) {
      const int o = offsets[i] + add;
      offsets[i] = o;
      pos[i] = o;
    }
  }
  if (blockIdx.x == 0 && t == 0) offsets[n] = n_edges;
}

// ---------------------------------------------------------------------------
// scatter: pairs[slot] = {src, bits(weight)} in dst-sorted order.
// ---------------------------------------------------------------------------
__global__ __launch_bounds__(256) void scatter_kernel(
    const int* __restrict__ esrc, const int* __restrict__ edst,
    const float* __restrict__ ew, int* __restrict__ pos,
    int2* __restrict__ pairs, int n_edges) {
  const int e = blockIdx.x * 256 + threadIdx.x;
  if (e >= n_edges) return;
  const int d = edst[e];
  const int slot = atomicAdd(&pos[d], 1);
  pairs[slot] = make_int2(esrc[e], __float_as_int(ew[e]));
}

// ---------------------------------------------------------------------------
// sage_out v2: fused root-GEMM + aggregation, EDGE-PARALLEL gather.
//   prologue: prefetch chunk-0 pairs + full h rows into registers
//             (256 threads x up to 2 tasks x 4 dwordx4 -> massive MLP,
//              latency hides under the MFMA phase)
//   phase 1 : MFMA x @ Wr + bsum -> ot[16][128] in LDS (unchanged)
//   phase 2 : dump prefetched rows to LDS H[KC][272B] (row-padded, aliases xs),
//             then per-node accumulation reads LDS (60-120cy, pipelined)
//             instead of chasing L3 per edge (~600cy dependent chain).
//   >94% of blocks (Poisson(96) edges/16-node tile) need exactly one chunk;
//   generic chunk loop stages directly for the tail.
// ---------------------------------------------------------------------------
__global__ __launch_bounds__(256, 4) void sage_out(
    const float* __restrict__ x, const __hip_bfloat16* __restrict__ WTr,
    const float* __restrict__ bsum, const __hip_bfloat16* __restrict__ h,
    const int* __restrict__ offsets, const int2* __restrict__ pairs,
    float* __restrict__ out) {
  __shared__ float ot[16][D];                       // 8 KB
  __shared__ float wbuf[KC];                        // 448 B
  __shared__ __align__(16) char Hbuf[KC * HROW];    // 30464 B, aliases xs
  __hip_bfloat16 (*xs)[136] = reinterpret_cast<__hip_bfloat16(*)[136]>(Hbuf);

  const int t = threadIdx.x;
  const int wave = t >> 6;
  const int lane = t & 63;
  const int m = lane & 15;
  const int q = lane >> 4;
  const int rowbase = blockIdx.x * 16;

  // ---- edge-range metadata (issue these dependent loads as early as possible)
  const int gB0 = offsets[rowbase];
  const int Eb = offsets[rowbase + 16] - gB0;
  int nb[4], ne[4];
#pragma unroll
  for (int j = 0; j < 4; ++j) {
    nb[j] = offsets[rowbase + wave * 4 + j] - gB0;
    ne[j] = offsets[rowbase + wave * 4 + j + 1] - gB0;
  }

  // ---- chunk-0 prefetch: task tau covers 64B quarter (tau&3) of edge (tau>>2)
  const int cnt0 = Eb < KC ? Eb : KC;
  const int le0 = t >> 2;
  const int le1 = (t + 256) >> 2;
  const int qt = t & 3;
  const bool v0 = le0 < cnt0;
  const bool v1 = le1 < cnt0;
  int2 pr0 = make_int2(0, 0), pr1 = make_int2(0, 0);
  int4 g0[4], g1[4];
  if (v0) {
    pr0 = pairs[gB0 + le0];
    const int4* p = (const int4*)((const char*)h + ((size_t)(unsigned)pr0.x << 8) + (qt << 6));
#pragma unroll
    for (int i = 0; i < 4; ++i) g0[i] = p[i];
  }
  if (v1) {
    pr1 = pairs[gB0 + le1];
    const int4* p = (const int4*)((const char*)h + ((size_t)(unsigned)pr1.x << 8) + (qt << 6));
#pragma unroll
    for (int i = 0; i < 4; ++i) g1[i] = p[i];
  }

  // ---- phase 1: root GEMM (unchanged) ----
  short8 bfrag[2][4];
#pragma unroll
  for (int c = 0; c < 2; ++c) {
    const int n0 = wave * 32 + c * 16;
#pragma unroll
    for (int ks = 0; ks < 4; ++ks)
      bfrag[c][ks] = *(const short8*)&WTr[(n0 + m) * D + ks * 32 + q * 8];
  }

  {
    const int srow = t >> 4;
    const int scol = (t & 15) * 8;
    const float4* src = (const float4*)&x[(size_t)(rowbase + srow) * D + scol];
    const float4 v0f = src[0], v1f = src[1];
    __hip_bfloat16* dst = &xs[srow][scol];
    dst[0] = __float2bfloat16(v0f.x); dst[1] = __float2bfloat16(v0f.y);
    dst[2] = __float2bfloat16(v0f.z); dst[3] = __float2bfloat16(v0f.w);
    dst[4] = __float2bfloat16(v1f.x); dst[5] = __float2bfloat16(v1f.y);
    dst[6] = __float2bfloat16(v1f.z); dst[7] = __float2bfloat16(v1f.w);
  }
  __syncthreads();

  f32x4 acc[2];
#pragma unroll
  for (int c = 0; c < 2; ++c)
#pragma unroll
    for (int r = 0; r < 4; ++r) acc[c][r] = 0.f;

#pragma unroll
  for (int ks = 0; ks < 4; ++ks) {
    const short8 afrag = *(const short8*)&xs[m][ks * 32 + q * 8];
#pragma unroll
    for (int c = 0; c < 2; ++c)
      acc[c] = __builtin_amdgcn_mfma_f32_16x16x32_bf16(afrag, bfrag[c][ks], acc[c], 0, 0, 0);
  }

#pragma unroll
  for (int c = 0; c < 2; ++c) {
    const int n = wave * 32 + c * 16 + m;
    const float b = bsum[n];
#pragma unroll
    for (int r = 0; r < 4; ++r)
      ot[q * 4 + r][n] = acc[c][r] + b;
  }
  __syncthreads();   // MFMA xs-reads done -> Hbuf (alias) may be written

  // ---- phase 2: chunked LDS-staged aggregation ----
  float2 a[4];
#pragma unroll
  for (int j = 0; j < 4; ++j) a[j] = make_float2(0.f, 0.f);

  for (int base = 0; base < Eb; base += KC) {
    const int cnt = (Eb - base) < KC ? (Eb - base) : KC;
    if (base == 0) {
      // dump prefetched chunk 0
      if (v0) {
        char* dst = &Hbuf[le0 * HROW + (qt << 6)];
#pragma unroll
        for (int i = 0; i < 4; ++i) ((int4*)dst)[i] = g0[i];
        if (qt == 0) wbuf[le0] = __int_as_float(pr0.y);
      }
      if (v1) {
        char* dst = &Hbuf[le1 * HROW + (qt << 6)];
#pragma unroll
        for (int i = 0; i < 4; ++i) ((int4*)dst)[i] = g1[i];
        if (qt == 0) wbuf[le1] = __int_as_float(pr1.y);
      }
    } else {
      __syncthreads();   // previous chunk's accumulation reads done
#pragma unroll
      for (int s = 0; s < 2; ++s) {
        const int le = (t + s * 256) >> 2;
        if (le < cnt) {
          const int2 pr = pairs[gB0 + base + le];
          const int4* p = (const int4*)((const char*)h + ((size_t)(unsigned)pr.x << 8) + (qt << 6));
          int4 g[4];
#pragma unroll
          for (int i = 0; i < 4; ++i) g[i] = p[i];
          char* dst = &Hbuf[le * HROW + (qt << 6)];
#pragma unroll
          for (int i = 0; i < 4; ++i) ((int4*)dst)[i] = g[i];
          if (qt == 0) wbuf[le] = __int_as_float(pr.y);
        }
      }
    }
    __syncthreads();

    // per-node accumulation out of LDS; wave handles nodes wave*4 + 0..3,
    // lane covers cols {2*lane, 2*lane+1}. 1-deep software pipeline.
#pragma unroll
    for (int j = 0; j < 4; ++j) {
      const int lo = nb[j] > base ? nb[j] : base;
      const int hi0 = base + cnt;
      const int hi = ne[j] < hi0 ? ne[j] : hi0;
      if (lo < hi) {
        int li = lo - base;
        float w = wbuf[li];
        __hip_bfloat162 hv = *(const __hip_bfloat162*)&Hbuf[li * HROW + lane * 4];
        for (int i = lo + 1; i < hi; ++i) {
          const int lj = i - base;
          const float nw = wbuf[lj];
          const __hip_bfloat162 nv = *(const __hip_bfloat162*)&Hbuf[lj * HROW + lane * 4];
          a[j].x = fmaf(w, __bfloat162float(hv.x), a[j].x);
          a[j].y = fmaf(w, __bfloat162float(hv.y), a[j].y);
          w = nw; hv = nv;
        }
        a[j].x = fmaf(w, __bfloat162float(hv.x), a[j].x);
        a[j].y = fmaf(w, __bfloat162float(hv.y), a[j].y);
      }
    }
  }

  // epilogue: out = ot + agg (ot stable since phase-1 barrier)
#pragma unroll
  for (int j = 0; j < 4; ++j) {
    const int ln = wave * 4 + j;
    float2 o = *(const float2*)&ot[ln][2 * lane];
    o.x += a[j].x;
    o.y += a[j].y;
    *(float2*)&out[(size_t)(rowbase + ln) * D + 2 * lane] = o;
  }
}

// ---------------------------------------------------------------------------
extern "C" void kernel_launch(void* const* d_in, const int* in_sizes, int n_in,
                              void* d_out, int out_size, void* d_ws, size_t ws_size,
                              hipStream_t stream) {
  const float* x   = (const float*)d_in[0];
  const int* esrc  = (const int*)d_in[1];
  const int* edst  = (const int*)d_in[2];
  const float* ew  = (const float*)d_in[3];
  const float* Wl  = (const float*)d_in[4];
  const float* bl  = (const float*)d_in[5];
  const float* Wr  = (const float*)d_in[6];
  const float* br  = (const float*)d_in[7];
  float* out = (float*)d_out;

  const int n_nodes = in_sizes[0] / D;   // 100000
  const int n_edges = in_sizes[1];       // 600000

  // Workspace layout (16B aligned sections)
  char* ws = (char*)d_ws;
  size_t off = 0;
  __hip_bfloat16* h = (__hip_bfloat16*)(ws + off);      // 25.6 MB
  off += (size_t)n_nodes * D * sizeof(__hip_bfloat16);
  off = (off + 15) & ~15ull;
  int* offsets = (int*)(ws + off);
  off += (size_t)(n_nodes + 1) * sizeof(int);
  off = (off + 15) & ~15ull;
  int* pos = (int*)(ws + off);                          // degree, then cursors
  off += (size_t)n_nodes * sizeof(int);
  off = (off + 15) & ~15ull;
  int* partials = (int*)(ws + off);
  off += 1024 * sizeof(int);
  off = (off + 15) & ~15ull;
  int2* pairs = (int2*)(ws + off);                      // 4.8 MB
  off += (size_t)n_edges * sizeof(int2);
  off = (off + 15) & ~15ull;
  __hip_bfloat16* WTl = (__hip_bfloat16*)(ws + off);
  off += (size_t)D * D * sizeof(__hip_bfloat16);
  __hip_bfloat16* WTr = (__hip_bfloat16*)(ws + off);
  off += (size_t)D * D * sizeof(__hip_bfloat16);
  float* bsum = (float*)(ws + off);
  off += D * sizeof(float);

  const int n_rowtiles = (n_nodes + 15) / 16;           // 6250 (exact)

  hipMemsetAsync(pos, 0, (size_t)n_nodes * sizeof(int), stream);
  prep_w<<<128, 256, 0, stream>>>(Wl, Wr, bl, br, WTl, WTr, bsum);

  const int gemm_grid = n_rowtiles < 2048 ? n_rowtiles : 2048;
  gemm_h<<<gemm_grid, 256, 0, stream>>>(x, WTl, h, edst, pos, n_edges, n_rowtiles);

  const int nparts = (n_nodes + SCAN_TILE - 1) / SCAN_TILE;   // 98
  scan1_kernel<<<nparts, SCAN_BLK, 0, stream>>>(pos, offsets, partials, n_nodes);
  scan3_kernel<<<nparts, SCAN_BLK, 0, stream>>>(offsets, pos, partials, n_nodes, n_edges);
  scatter_kernel<<<(n_edges + 255) / 256, 256, 0, stream>>>(esrc, edst, ew, pos, pairs, n_edges);

  sage_out<<<n_rowtiles, 256, 0, stream>>>(x, WTr, bsum, h, offsets, pairs, out);
}

// Round 2
// 241.908 us; speedup vs baseline: 1.1153x; 1.1153x over previous
//
#include <hip/hip_runtime.h>
#include <hip/hip_bf16.h>

#define D 128
#define SCAN_BLK 256
#define SCAN_VPT 4
#define SCAN_TILE (SCAN_BLK * SCAN_VPT)   // 1024 elements per scan block

#define KC 112          // edges per LDS chunk in sage_out (16-divisible)
#define EW (KC / 4)     // edges staged per wave per chunk = 28
#define NI (EW / 4)     // global_load_lds issues per wave per chunk = 7

typedef __attribute__((ext_vector_type(8))) short short8;   // 8 bf16 = 4 VGPR
typedef __attribute__((ext_vector_type(4))) float f32x4;    // MFMA C/D frag

// DMA one 16B/lane slice global->LDS. Global addr is per-lane (gather),
// LDS dest is wave-uniform base; HW writes lane l at base + l*16.
__device__ __forceinline__ void gld16(const void* g, void* l) {
  __builtin_amdgcn_global_load_lds(
      (const __attribute__((address_space(1))) void*)g,
      (__attribute__((address_space(3))) void*)l, 16, 0, 0);
}

// ---------------------------------------------------------------------------
// prep_w: WTl/WTr = bf16 transpose of Wl/Wr ([n][k] layout, 16B B-fragments);
// bsum = bl + br.
// ---------------------------------------------------------------------------
__global__ __launch_bounds__(256) void prep_w(
    const float* __restrict__ Wl, const float* __restrict__ Wr,
    const float* __restrict__ bl, const float* __restrict__ br,
    __hip_bfloat16* __restrict__ WTl, __hip_bfloat16* __restrict__ WTr,
    float* __restrict__ bsum) {
  const int tid = blockIdx.x * 256 + threadIdx.x;  // grid 128 -> 0..32767
  const int n = (tid >> 7) & 127;
  const int k = tid & 127;
  if (tid < 16384) {
    WTl[n * D + k] = __float2bfloat16(Wl[k * D + n]);
  } else {
    WTr[n * D + k] = __float2bfloat16(Wr[k * D + n]);
  }
  if (tid < 128) bsum[tid] = bl[tid] + br[tid];
}

// ---------------------------------------------------------------------------
// gemm_h: h = bf16(x @ Wl). Also absorbs the degree histogram as a
// grid-stride prologue (atomics overlap with other waves' MFMA).
// ---------------------------------------------------------------------------
__global__ __launch_bounds__(256) void gemm_h(
    const float* __restrict__ x, const __hip_bfloat16* __restrict__ WTl,
    __hip_bfloat16* __restrict__ h,
    const int* __restrict__ edst, int* __restrict__ deg, int n_edges,
    int n_rowtiles) {
  const int gsz = gridDim.x * 256;
  for (int e = blockIdx.x * 256 + threadIdx.x; e < n_edges; e += gsz)
    atomicAdd(&deg[edst[e]], 1);

  __shared__ __hip_bfloat16 xs[16][136];   // +8 pad
  const int t = threadIdx.x;
  const int wave = t >> 6;
  const int lane = t & 63;
  const int m = lane & 15;
  const int q = lane >> 4;

  short8 bfrag[2][4];
#pragma unroll
  for (int c = 0; c < 2; ++c) {
    const int n0 = wave * 32 + c * 16;
#pragma unroll
    for (int ks = 0; ks < 4; ++ks)
      bfrag[c][ks] = *(const short8*)&WTl[(n0 + m) * D + ks * 32 + q * 8];
  }

  const int srow = t >> 4;
  const int scol = (t & 15) * 8;

  for (int rt = blockIdx.x; rt < n_rowtiles; rt += gridDim.x) {
    const int rowbase = rt * 16;
    {
      const float4* src = (const float4*)&x[(size_t)(rowbase + srow) * D + scol];
      const float4 v0 = src[0], v1 = src[1];
      __hip_bfloat16* dst = &xs[srow][scol];
      dst[0] = __float2bfloat16(v0.x); dst[1] = __float2bfloat16(v0.y);
      dst[2] = __float2bfloat16(v0.z); dst[3] = __float2bfloat16(v0.w);
      dst[4] = __float2bfloat16(v1.x); dst[5] = __float2bfloat16(v1.y);
      dst[6] = __float2bfloat16(v1.z); dst[7] = __float2bfloat16(v1.w);
    }
    __syncthreads();

    f32x4 acc[2];
#pragma unroll
    for (int c = 0; c < 2; ++c)
#pragma unroll
      for (int r = 0; r < 4; ++r) acc[c][r] = 0.f;

#pragma unroll
    for (int ks = 0; ks < 4; ++ks) {
      const short8 afrag = *(const short8*)&xs[m][ks * 32 + q * 8];
#pragma unroll
      for (int c = 0; c < 2; ++c)
        acc[c] = __builtin_amdgcn_mfma_f32_16x16x32_bf16(afrag, bfrag[c][ks], acc[c], 0, 0, 0);
    }

#pragma unroll
    for (int c = 0; c < 2; ++c) {
      const int n = wave * 32 + c * 16 + m;
#pragma unroll
      for (int r = 0; r < 4; ++r)
        h[(size_t)(rowbase + q * 4 + r) * D + n] = __float2bfloat16(acc[c][r]);
    }
    __syncthreads();
  }
}

// ---------------------------------------------------------------------------
// scan1: block-level exclusive scan of deg -> offsets + per-block totals.
// ---------------------------------------------------------------------------
__global__ __launch_bounds__(SCAN_BLK) void scan1_kernel(
    const int* __restrict__ deg, int* __restrict__ offsets,
    int* __restrict__ partials, int n) {
  __shared__ int sdata[SCAN_BLK];
  const int t = threadIdx.x;
  const int base = blockIdx.x * SCAN_TILE + t * SCAN_VPT;

  int v[SCAN_VPT];
  int s = 0;
#pragma unroll
  for (int j = 0; j < SCAN_VPT; ++j) {
    v[j] = (base + j < n) ? deg[base + j] : 0;
    s += v[j];
  }
  sdata[t] = s;
  __syncthreads();
  for (int off = 1; off < SCAN_BLK; off <<= 1) {
    int xv = (t >= off) ? sdata[t - off] : 0;
    __syncthreads();
    sdata[t] += xv;
    __syncthreads();
  }
  int excl = sdata[t] - s;
  if (t == SCAN_BLK - 1) partials[blockIdx.x] = sdata[t];
  int run = excl;
#pragma unroll
  for (int j = 0; j < SCAN_VPT; ++j) {
    if (base + j < n) offsets[base + j] = run;
    run += v[j];
  }
}

// ---------------------------------------------------------------------------
// scan3: adds block-prefix (scan2 folded in), materializes pos[] cursors.
// ---------------------------------------------------------------------------
__global__ __launch_bounds__(SCAN_BLK) void scan3_kernel(
    int* __restrict__ offsets, int* __restrict__ pos,
    const int* __restrict__ partials, int n, int n_edges) {
  __shared__ int s_add;
  const int t = threadIdx.x;
  if (t < 64) {
    int v = 0;
    for (int j = t; j < blockIdx.x; j += 64) v += partials[j];
#pragma unroll
    for (int off = 32; off > 0; off >>= 1) v += __shfl_down(v, off);
    if (t == 0) s_add = v;
  }
  __syncthreads();
  const int add = s_add;
  const int base = blockIdx.x * SCAN_TILE + t * SCAN_VPT;
#pragma unroll
  for (int j = 0; j < SCAN_VPT; ++j) {
    const int i = base + j;
    if (i < n) {
      const int o = offsets[i] + add;
      offsets[i] = o;
      pos[i] = o;
    }
  }
  if (blockIdx.x == 0 && t == 0) offsets[n] = n_edges;
}

// ---------------------------------------------------------------------------
// scatter: pairs[slot] = {src, bits(weight)} in dst-sorted order.
// ---------------------------------------------------------------------------
__global__ __launch_bounds__(256) void scatter_kernel(
    const int* __restrict__ esrc, const int* __restrict__ edst,
    const float* __restrict__ ew, int* __restrict__ pos,
    int2* __restrict__ pairs, int n_edges) {
  const int e = blockIdx.x * 256 + threadIdx.x;
  if (e >= n_edges) return;
  const int d = edst[e];
  const int slot = atomicAdd(&pos[d], 1);
  pairs[slot] = make_int2(esrc[e], __float_as_int(ew[e]));
}

// ---------------------------------------------------------------------------
// sage_out v3: fused root-GEMM + aggregation; edge-parallel gather staged
// via global_load_lds DMA (no VGPRs on the gather path -> no spill).
//   phase 1: MFMA x @ Wr + bsum -> ot[16][128] (xs staging in smem)
//   phase 2: per KC=112-edge chunk: per-lane-gather h rows straight into
//            smem rows (256B stride, linear dest as HW requires), then
//            per-node accumulation reads LDS (2 lanes/bank = conflict-free).
//   Poisson(96) edges/tile -> ~94% of blocks need exactly one chunk.
//   LDS 37.3 KB -> 4 blocks/CU; TLP hides the one stage round per block.
// ---------------------------------------------------------------------------
__global__ __launch_bounds__(256, 4) void sage_out(
    const float* __restrict__ x, const __hip_bfloat16* __restrict__ WTr,
    const float* __restrict__ bsum, const __hip_bfloat16* __restrict__ h,
    const int* __restrict__ offsets, const int2* __restrict__ pairs,
    float* __restrict__ out) {
  __shared__ float ot[16][D];                       // 8 KB
  __shared__ float wbuf[KC];                        // 448 B
  __shared__ __align__(16) char smem[KC * 256];     // 28 KB; aliases xs
  __hip_bfloat16 (*xs)[136] = reinterpret_cast<__hip_bfloat16(*)[136]>(smem);

  const int t = threadIdx.x;
  const int wave = t >> 6;
  const int lane = t & 63;
  const int m = lane & 15;
  const int q = lane >> 4;
  const int rowbase = blockIdx.x * 16;

  const int gB0 = offsets[rowbase];
  const int Eb = offsets[rowbase + 16] - gB0;
  int nb[4], ne[4];
#pragma unroll
  for (int j = 0; j < 4; ++j) {
    nb[j] = offsets[rowbase + wave * 4 + j] - gB0;
    ne[j] = offsets[rowbase + wave * 4 + j + 1] - gB0;
  }

  // ---- phase 1: root GEMM ----
  short8 bfrag[2][4];
#pragma unroll
  for (int c = 0; c < 2; ++c) {
    const int n0 = wave * 32 + c * 16;
#pragma unroll
    for (int ks = 0; ks < 4; ++ks)
      bfrag[c][ks] = *(const short8*)&WTr[(n0 + m) * D + ks * 32 + q * 8];
  }

  {
    const int srow = t >> 4;
    const int scol = (t & 15) * 8;
    const float4* src = (const float4*)&x[(size_t)(rowbase + srow) * D + scol];
    const float4 v0 = src[0], v1 = src[1];
    __hip_bfloat16* dst = &xs[srow][scol];
    dst[0] = __float2bfloat16(v0.x); dst[1] = __float2bfloat16(v0.y);
    dst[2] = __float2bfloat16(v0.z); dst[3] = __float2bfloat16(v0.w);
    dst[4] = __float2bfloat16(v1.x); dst[5] = __float2bfloat16(v1.y);
    dst[6] = __float2bfloat16(v1.z); dst[7] = __float2bfloat16(v1.w);
  }
  __syncthreads();

  f32x4 acc[2];
#pragma unroll
  for (int c = 0; c < 2; ++c)
#pragma unroll
    for (int r = 0; r < 4; ++r) acc[c][r] = 0.f;

#pragma unroll
  for (int ks = 0; ks < 4; ++ks) {
    const short8 afrag = *(const short8*)&xs[m][ks * 32 + q * 8];
#pragma unroll
    for (int c = 0; c < 2; ++c)
      acc[c] = __builtin_amdgcn_mfma_f32_16x16x32_bf16(afrag, bfrag[c][ks], acc[c], 0, 0, 0);
  }

#pragma unroll
  for (int c = 0; c < 2; ++c) {
    const int n = wave * 32 + c * 16 + m;
    const float b = bsum[n];
#pragma unroll
    for (int r = 0; r < 4; ++r)
      ot[q * 4 + r][n] = acc[c][r] + b;
  }
  __syncthreads();   // xs reads + ot writes done -> smem reusable for gather

  // ---- phase 2: chunked DMA-staged aggregation ----
  float2 a[4];
#pragma unroll
  for (int j = 0; j < 4; ++j) a[j] = make_float2(0.f, 0.f);

  for (int base = 0; base < Eb; base += KC) {
    const int cnt = (Eb - base) < KC ? (Eb - base) : KC;
    const int r0 = wave * EW;   // this wave's first chunk-local row

    // load this wave's pair metadata (4 distinct pairs per issue, L1-broadcast)
    int srcs[NI];
    float wts[NI];
#pragma unroll
    for (int i = 0; i < NI; ++i) {
      const int row = r0 + i * 4 + q;          // chunk-local edge this lane covers
      const int ei = base + row;
      const int ce = ei < Eb ? ei : Eb - 1;    // clamp: duplicate row, unused
      const int2 pr = pairs[gB0 + ce];
      srcs[i] = pr.x;
      wts[i] = __int_as_float(pr.y);
    }
    // DMA gather: 4 h-rows per issue (64 lanes x 16B = 1KB -> rows r0+i*4..+3)
#pragma unroll
    for (int i = 0; i < NI; ++i) {
      if (r0 + i * 4 < cnt) {                  // wave-uniform skip of dead issues
        gld16((const char*)h + ((size_t)(unsigned)srcs[i] << 8) + (m << 4),
              smem + (size_t)(r0 + i * 4) * 256);
      }
    }
    // per-edge weights
#pragma unroll
    for (int i = 0; i < NI; ++i) {
      const int row = r0 + i * 4 + q;
      if (m == 0 && row < cnt) wbuf[row] = wts[i];
    }
    __syncthreads();   // drains vmcnt(0): DMA'd rows + wbuf visible

    // per-node accumulation out of LDS; wave owns nodes wave*4 + 0..3,
    // lane covers cols {2*lane, 2*lane+1}; 2 lanes/bank -> conflict-free.
#pragma unroll
    for (int j = 0; j < 4; ++j) {
      const int lo = nb[j] > base ? nb[j] : base;
      const int hi0 = base + cnt;
      const int hi = ne[j] < hi0 ? ne[j] : hi0;
      for (int i = lo; i < hi; ++i) {
        const int li = i - base;
        const float w = wbuf[li];
        const __hip_bfloat162 hv =
            *(const __hip_bfloat162*)&smem[(size_t)li * 256 + lane * 4];
        a[j].x = fmaf(w, __bfloat162float(hv.x), a[j].x);
        a[j].y = fmaf(w, __bfloat162float(hv.y), a[j].y);
      }
    }
    if (base + KC < Eb) __syncthreads();   // protect smem before next stage
  }

  // epilogue: out = ot + agg
#pragma unroll
  for (int j = 0; j < 4; ++j) {
    const int ln = wave * 4 + j;
    float2 o = *(const float2*)&ot[ln][2 * lane];
    o.x += a[j].x;
    o.y += a[j].y;
    *(float2*)&out[(size_t)(rowbase + ln) * D + 2 * lane] = o;
  }
}

// ---------------------------------------------------------------------------
extern "C" void kernel_launch(void* const* d_in, const int* in_sizes, int n_in,
                              void* d_out, int out_size, void* d_ws, size_t ws_size,
                              hipStream_t stream) {
  const float* x   = (const float*)d_in[0];
  const int* esrc  = (const int*)d_in[1];
  const int* edst  = (const int*)d_in[2];
  const float* ew  = (const float*)d_in[3];
  const float* Wl  = (const float*)d_in[4];
  const float* bl  = (const float*)d_in[5];
  const float* Wr  = (const float*)d_in[6];
  const float* br  = (const float*)d_in[7];
  float* out = (float*)d_out;

  const int n_nodes = in_sizes[0] / D;   // 100000
  const int n_edges = in_sizes[1];       // 600000

  // Workspace layout (16B aligned sections)
  char* ws = (char*)d_ws;
  size_t off = 0;
  __hip_bfloat16* h = (__hip_bfloat16*)(ws + off);      // 25.6 MB
  off += (size_t)n_nodes * D * sizeof(__hip_bfloat16);
  off = (off + 15) & ~15ull;
  int* offsets = (int*)(ws + off);
  off += (size_t)(n_nodes + 1) * sizeof(int);
  off = (off + 15) & ~15ull;
  int* pos = (int*)(ws + off);                          // degree, then cursors
  off += (size_t)n_nodes * sizeof(int);
  off = (off + 15) & ~15ull;
  int* partials = (int*)(ws + off);
  off += 1024 * sizeof(int);
  off = (off + 15) & ~15ull;
  int2* pairs = (int2*)(ws + off);                      // 4.8 MB
  off += (size_t)n_edges * sizeof(int2);
  off = (off + 15) & ~15ull;
  __hip_bfloat16* WTl = (__hip_bfloat16*)(ws + off);
  off += (size_t)D * D * sizeof(__hip_bfloat16);
  __hip_bfloat16* WTr = (__hip_bfloat16*)(ws + off);
  off += (size_t)D * D * sizeof(__hip_bfloat16);
  float* bsum = (float*)(ws + off);
  off += D * sizeof(float);

  const int n_rowtiles = (n_nodes + 15) / 16;           // 6250 (exact)

  hipMemsetAsync(pos, 0, (size_t)n_nodes * sizeof(int), stream);
  prep_w<<<128, 256, 0, stream>>>(Wl, Wr, bl, br, WTl, WTr, bsum);

  const int gemm_grid = n_rowtiles < 2048 ? n_rowtiles : 2048;
  gemm_h<<<gemm_grid, 256, 0, stream>>>(x, WTl, h, edst, pos, n_edges, n_rowtiles);

  const int nparts = (n_nodes + SCAN_TILE - 1) / SCAN_TILE;   // 98
  scan1_kernel<<<nparts, SCAN_BLK, 0, stream>>>(pos, offsets, partials, n_nodes);
  scan3_kernel<<<nparts, SCAN_BLK, 0, stream>>>(offsets, pos, partials, n_nodes, n_edges);
  scatter_kernel<<<(n_edges + 255) / 256, 256, 0, stream>>>(esrc, edst, ew, pos, pairs, n_edges);

  sage_out<<<n_rowtiles, 256, 0, stream>>>(x, WTr, bsum, h, offsets, pairs, out);
}